// Round 8
// baseline (323.115 us; speedup 1.0000x reference)
//
#include <hip/hip_runtime.h>
#include <math.h>

typedef float f32x4 __attribute__((ext_vector_type(4)));

// out layout: d_out[0..N) = final_score (f32), d_out[N] = loss (f32)
// ws layout (H==768 fast path): pooled f32[N*H]
// ws layout (generic path):     pooled f32[N*H] | starts i32[B+1] | seg i32[N]

// ---------------- Kernel B: wave-per-row masked avg-pool -----------------
// unroll 8 => 24 dwordx4 in flight per wave (round-4 proven config; round-5
// showed fewer in-flight loads regresses even with higher occupancy).
// Round-8 A/B: nontemporal hint REMOVED (isolated test; added unisolated in
// round 2).
__global__ __launch_bounds__(256, 4)
void pool_kernel_h768(const float* __restrict__ lhs,
                      const float* __restrict__ mask,
                      float* __restrict__ pooled,
                      float* __restrict__ loss,
                      int N, int S) {
    const int Hv = 192;
    if (blockIdx.x == 0 && threadIdx.x == 0) *loss = 0.f;

    const int wid  = threadIdx.x >> 6;
    const int lane = threadIdx.x & 63;
    const int j = blockIdx.x * 4 + wid;
    if (j >= N) return;

    const f32x4* row  = (const f32x4*)(lhs + (size_t)j * S * 768) + lane;
    const float* mrow = mask + (size_t)j * S;

    f32x4 a0 = {0.f,0.f,0.f,0.f}, a1 = a0, a2 = a0;
    float msum = 0.f;
#pragma unroll 8
    for (int s = 0; s < S; ++s) {
        float m = mrow[s];                  // wave-uniform addr -> 1 req/wave
        const f32x4* p = row + (size_t)s * Hv;
        f32x4 v0 = p[0];
        f32x4 v1 = p[64];
        f32x4 v2 = p[128];
        a0 += v0 * m; a1 += v1 * m; a2 += v2 * m;
        msum += m;
    }
    const float inv = 1.0f / msum;
    f32x4* prow = (f32x4*)(pooled + (size_t)j * 768);
    prow[lane]       = a0 * inv;
    prow[lane + 64]  = a1 * inv;
    prow[lane + 128] = a2 * inv;
}

// ---------------- Kernel C (H==768): one block per n-best group ----------
// sz<=32 hot path: register-blocked sim GEMM. Thread owns (j, 4 r-rows):
// pj[k] read once from LDS, reused 4x; pi[r][k] are half-wave-uniform
// global loads (L1/L2-served). (Round-7 win: -17us.)
#define MAX_ROWS 40
#define PADV 193          // f32x4 units per LDS row; PADV%8==1 avoids full-bank overlap
#define MAX_SC 256

__global__ __launch_bounds__(256)
void group_kernel(const float* __restrict__ pooler,
                  const float* __restrict__ pooled,
                  const float* __restrict__ am,
                  const float* __restrict__ ctc,
                  const float* __restrict__ W,
                  const float* __restrict__ bb,
                  const float* __restrict__ labels,
                  const int* __restrict__ nbest,
                  float* __restrict__ score,
                  float* __restrict__ loss,
                  int N, int B) {
    __shared__ f32x4 s_pool[MAX_ROWS * PADV];   // ~123.5 KB
    __shared__ int   s_nb[1024];
    __shared__ float s_score[MAX_SC];
    __shared__ int   sh_s0, sh_sz;
    __shared__ float blk_loss;

    const int g = blockIdx.x;
    const int t = threadIdx.x;

    for (int i = t; i < B; i += 256) s_nb[i] = nbest[i];
    __syncthreads();
    if (t == 0) {
        int off = 0;
        for (int i = 0; i < g; ++i) off += s_nb[i];
        sh_s0 = off; sh_sz = s_nb[g];
        blk_loss = 0.f;
    }
    __syncthreads();
    const int s0 = sh_s0, sz = sh_sz;

    const int wid  = t >> 6;
    const int lane = t & 63;

    // ---- per-row linear score: [pooler_r, am_r, ctc_r] @ W + b ----------
    const f32x4* Wv = (const f32x4*)W;
    for (int r = wid; r < sz; r += 4) {
        const f32x4* pr = (const f32x4*)(pooler + (size_t)(s0 + r) * 768);
        f32x4 ps = pr[lane]       * Wv[lane]
                 + pr[lane + 64]  * Wv[lane + 64]
                 + pr[lane + 128] * Wv[lane + 128];
        float a = ps.x + ps.y + ps.z + ps.w;
        for (int d = 32; d > 0; d >>= 1) a += __shfl_xor(a, d, 64);
        if (lane == 0) {
            float sc = a + am[s0 + r] * W[768] + ctc[s0 + r] * W[769] + bb[0];
            if (sz <= MAX_SC) s_score[r] = sc;
            score[s0 + r] = sc;
        }
    }

    // ---- stage pooled group rows in LDS ---------------------------------
    const f32x4* pooled4 = (const f32x4*)pooled;
    const bool staged = (sz <= MAX_ROWS);
    if (staged) {
        for (int idx = t; idx < sz * 192; idx += 256) {
            int r = idx / 192, c = idx - r * 192;
            s_pool[r * PADV + c] = pooled4[(size_t)(s0 + r) * 192 + c];
        }
    }
    __syncthreads();

    if (sz <= 32) {
        // register-blocked: thread -> (j = lane&31, r in {r0..r0+3})
        const int j    = lane & 31;
        const int half = lane >> 5;
        const int r0   = (wid * 2 + half) * 4;
        const bool jok = (j < sz);
        const f32x4* pj = s_pool + (size_t)(jok ? j : 0) * PADV;
        const int rc0 = (r0 + 0 < sz) ? r0 + 0 : 0;
        const int rc1 = (r0 + 1 < sz) ? r0 + 1 : 0;
        const int rc2 = (r0 + 2 < sz) ? r0 + 2 : 0;
        const int rc3 = (r0 + 3 < sz) ? r0 + 3 : 0;
        const f32x4* pi0 = (const f32x4*)(pooler + (size_t)(s0 + rc0) * 768);
        const f32x4* pi1 = (const f32x4*)(pooler + (size_t)(s0 + rc1) * 768);
        const f32x4* pi2 = (const f32x4*)(pooler + (size_t)(s0 + rc2) * 768);
        const f32x4* pi3 = (const f32x4*)(pooler + (size_t)(s0 + rc3) * 768);
        f32x4 acc0 = {0.f,0.f,0.f,0.f}, acc1 = acc0, acc2 = acc0, acc3 = acc0;
#pragma unroll 4
        for (int k = 0; k < 192; ++k) {
            f32x4 pjv = pj[k];              // 1 LDS read, reused 4x
            acc0 += pi0[k] * pjv;           // half-wave-uniform global loads
            acc1 += pi1[k] * pjv;
            acc2 += pi2[k] * pjv;
            acc3 += pi3[k] * pjv;
        }
        float v0 = acc0.x + acc0.y + acc0.z + acc0.w;
        float v1 = acc1.x + acc1.y + acc1.z + acc1.w;
        float v2 = acc2.x + acc2.y + acc2.z + acc2.w;
        float v3 = acc3.x + acc3.y + acc3.z + acc3.w;
        float vv[4] = {v0, v1, v2, v3};
#pragma unroll
        for (int u = 0; u < 4; ++u) {
            const int  r   = r0 + u;
            const bool rok = (r < sz) && jok;
            float val = rok ? vv[u] : -INFINITY;
            float m = val;                  // 32-lane (half-wave) reduce
            for (int d = 1; d < 32; d <<= 1) m = fmaxf(m, __shfl_xor(m, d, 64));
            float e = rok ? expf(val - m) : 0.f;
            float ss = e;
            for (int d = 1; d < 32; d <<= 1) ss += __shfl_xor(ss, d, 64);
            if (rok && j == r)
                atomicAdd(&blk_loss, -(e / ss) / (float)B);
        }
    } else if (sz <= 64) {
        const f32x4* jbase  = staged ? s_pool : (pooled4 + (size_t)s0 * 192);
        const int    jstride = staged ? PADV : 192;
        for (int r = wid; r < sz; r += 4) {
            const bool jok = (lane < sz);
            const f32x4* pi = (const f32x4*)(pooler + (size_t)(s0 + r) * 768);
            const f32x4* pj = jbase + (size_t)(jok ? lane : 0) * jstride;
            f32x4 accA = {0.f,0.f,0.f,0.f}, accB = accA;
#pragma unroll 4
            for (int k = 0; k < 192; k += 2) {
                accA += pi[k]     * pj[k];
                accB += pi[k + 1] * pj[k + 1];
            }
            f32x4 acc4 = accA + accB;
            float val = jok ? (acc4.x + acc4.y + acc4.z + acc4.w) : -INFINITY;
            float m = val;
            for (int d = 1; d < 64; d <<= 1) m = fmaxf(m, __shfl_xor(m, d, 64));
            float e = jok ? expf(val - m) : 0.f;
            float ssum = e;
            for (int d = 1; d < 64; d <<= 1) ssum += __shfl_xor(ssum, d, 64);
            if (jok && lane == r)
                atomicAdd(&blk_loss, -(e / ssum) / (float)B);
        }
    } else {
        // generic chunked online-softmax fallback (slow path, unstaged)
        for (int r = wid; r < sz; r += 4) {
            const f32x4* pi = (const f32x4*)(pooler + (size_t)(s0 + r) * 768);
            float mrun = -INFINITY, srun = 0.f, dval = 0.f;
            for (int jc = 0; jc < sz; jc += 64) {
                const int  jx  = jc + lane;
                const bool jok = (jx < sz);
                const f32x4* pj = pooled4 + (size_t)(s0 + (jok ? jx : 0)) * 192;
                f32x4 accA = {0.f,0.f,0.f,0.f}, accB = accA;
                for (int k = 0; k < 192; k += 2) {
                    accA += pi[k]     * pj[k];
                    accB += pi[k + 1] * pj[k + 1];
                }
                f32x4 acc4 = accA + accB;
                float val = jok ? (acc4.x + acc4.y + acc4.z + acc4.w) : -INFINITY;
                float cm = val;
                for (int d = 1; d < 64; d <<= 1) cm = fmaxf(cm, __shfl_xor(cm, d, 64));
                float e = jok ? expf(val - cm) : 0.f;
                float cs = e;
                for (int d = 1; d < 64; d <<= 1) cs += __shfl_xor(cs, d, 64);
                float nm = fmaxf(mrun, cm);
                srun = srun * expf(mrun - nm) + cs * expf(cm - nm);
                float dv = __shfl(val, r - jc, 64);
                if (r >= jc && r < jc + 64) dval = dv;
                mrun = nm;
            }
            if (lane == 0)
                atomicAdd(&blk_loss, -(expf(dval - mrun) / srun) / (float)B);
        }
    }

    __syncthreads();
    // fused CE for this group (wave 0), scores from LDS
    if (wid == 0) {
        float m = -INFINITY;
        for (int idx = lane; idx < sz; idx += 64) {
            float sv = (sz <= MAX_SC) ? s_score[idx] : score[s0 + idx];
            m = fmaxf(m, sv);
        }
        for (int d = 1; d < 64; d <<= 1) m = fmaxf(m, __shfl_xor(m, d, 64));
        float s = 0.f;
        for (int idx = lane; idx < sz; idx += 64) {
            float sv = (sz <= MAX_SC) ? s_score[idx] : score[s0 + idx];
            s += expf(sv - m);
        }
        for (int d = 1; d < 64; d <<= 1) s += __shfl_xor(s, d, 64);
        const float ls = logf(s);
        float c = 0.f;
        for (int idx = lane; idx < sz; idx += 64) {
            float lb = labels[s0 + idx];
            if (lb != 0.f) {
                float sv = (sz <= MAX_SC) ? s_score[idx] : score[s0 + idx];
                c += lb * (sv - m - ls);
            }
        }
        for (int d = 1; d < 64; d <<= 1) c += __shfl_xor(c, d, 64);
        if (lane == 0) atomicAdd(&blk_loss, -c / (float)N);
    }
    __syncthreads();
    if (t == 0) atomicAdd(loss, blk_loss);
}

// =================== generic fallback path (H != 768) ====================
__global__ void seg_kernel(const int* __restrict__ nbest,
                           int* __restrict__ starts, int* __restrict__ seg,
                           float* __restrict__ loss, int B) {
    __shared__ int sh[1025];
    const int t = threadIdx.x;
    for (int g = t; g < B; g += blockDim.x) sh[g] = nbest[g];
    __syncthreads();
    if (t == 0) {
        int off = 0;
        for (int g = 0; g < B; ++g) { int v = sh[g]; sh[g] = off; off += v; }
        sh[B] = off;
        *loss = 0.f;
    }
    __syncthreads();
    for (int g = t; g <= B; g += blockDim.x) starts[g] = sh[g];
    for (int g = t; g < B; g += blockDim.x) {
        const int s0 = sh[g], s1 = sh[g + 1];
        for (int i = s0; i < s1; ++i) seg[i] = g;
    }
}

__global__ void pool_kernel_generic(const float* __restrict__ lhs,
                                    const float* __restrict__ mask,
                                    const float* __restrict__ pooler,
                                    const float* __restrict__ am,
                                    const float* __restrict__ ctc,
                                    const float* __restrict__ W,
                                    const float* __restrict__ bb,
                                    float* __restrict__ pooled,
                                    float* __restrict__ score,
                                    int S, int H) {
    const int j  = blockIdx.x;
    const int t  = threadIdx.x;
    const int Hv = H >> 2;
    const f32x4* row  = (const f32x4*)(lhs + (size_t)j * S * H);
    const float* mrow = mask + (size_t)j * S;
    f32x4 acc = {0.f,0.f,0.f,0.f};
    float msum = 0.f;
#pragma unroll 4
    for (int s = 0; s < S; ++s) {
        float m = mrow[s];
        acc += row[(size_t)s * Hv + t] * m;
        msum += m;
    }
    ((f32x4*)(pooled + (size_t)j * H))[t] = acc * (1.0f / msum);
    if (t < 64) {
        const f32x4* pr = (const f32x4*)(pooler + (size_t)j * H);
        const f32x4* Wv = (const f32x4*)W;
        float a = 0.f;
        for (int k = t; k < Hv; k += 64) {
            f32x4 p = pr[k] * Wv[k];
            a += p.x + p.y + p.z + p.w;
        }
        for (int d = 32; d > 0; d >>= 1) a += __shfl_xor(a, d, 64);
        if (t == 0)
            score[j] = a + am[j] * W[H] + ctc[j] * W[H + 1] + bb[0];
    }
}

__global__ void finale_kernel(const float* __restrict__ pooler,
                              const float* __restrict__ pooled,
                              const float* __restrict__ score,
                              const float* __restrict__ labels,
                              const int* __restrict__ starts,
                              const int* __restrict__ seg,
                              float* __restrict__ loss,
                              int H, int N, int B) {
    const int bid = blockIdx.x;
    if (bid >= N) {
        const int g = bid - N;
        const int lane = threadIdx.x;
        if (lane >= 64) return;
        const int s0 = starts[g], sz = starts[g + 1] - s0;
        float m = -INFINITY;
        for (int idx = lane; idx < sz; idx += 64) m = fmaxf(m, score[s0 + idx]);
        for (int d = 32; d > 0; d >>= 1) m = fmaxf(m, __shfl_xor(m, d, 64));
        float s = 0.f;
        for (int idx = lane; idx < sz; idx += 64) s += expf(score[s0 + idx] - m);
        for (int d = 32; d > 0; d >>= 1) s += __shfl_xor(s, d, 64);
        const float ls = logf(s);
        float c = 0.f;
        for (int idx = lane; idx < sz; idx += 64) {
            float lb = labels[s0 + idx];
            if (lb != 0.f) c += lb * (score[s0 + idx] - m - ls);
        }
        for (int d = 32; d > 0; d >>= 1) c += __shfl_xor(c, d, 64);
        if (lane == 0) atomicAdd(loss, -c / (float)N);
        return;
    }
    __shared__ float simv[512];
    const int i  = bid;
    const int g  = seg[i];
    const int s0 = starts[g], sz = starts[g + 1] - s0;
    const int wid = threadIdx.x >> 6, lane = threadIdx.x & 63;
    const int nw  = blockDim.x >> 6;
    const int Hv  = H >> 2;
    const f32x4* pi = (const f32x4*)(pooler + (size_t)i * H);
    for (int j = wid; j < sz; j += nw) {
        const f32x4* pj = (const f32x4*)(pooled + (size_t)(s0 + j) * H);
        float acc = 0.f;
        for (int k = lane; k < Hv; k += 64) {
            f32x4 p = pi[k] * pj[k];
            acc += p.x + p.y + p.z + p.w;
        }
        for (int d = 32; d > 0; d >>= 1) acc += __shfl_xor(acc, d, 64);
        if (lane == 0) simv[j] = acc;
    }
    __syncthreads();
    if (wid == 0) {
        float m = -INFINITY;
        for (int idx = lane; idx < sz; idx += 64) m = fmaxf(m, simv[idx]);
        for (int d = 32; d > 0; d >>= 1) m = fmaxf(m, __shfl_xor(m, d, 64));
        float s = 0.f;
        for (int idx = lane; idx < sz; idx += 64) s += expf(simv[idx] - m);
        for (int d = 32; d > 0; d >>= 1) s += __shfl_xor(s, d, 64);
        if (lane == 0) {
            const int p = i - s0;
            const float prob = expf(simv[p] - m) / s;
            atomicAdd(loss, -prob / (float)B);
        }
    }
}

extern "C" void kernel_launch(void* const* d_in, const int* in_sizes, int n_in,
                              void* d_out, int out_size, void* d_ws, size_t ws_size,
                              hipStream_t stream) {
    const float* pooler = (const float*)d_in[0];
    const float* lhs    = (const float*)d_in[1];
    const float* mask   = (const float*)d_in[2];
    const float* am     = (const float*)d_in[3];
    const float* ctc    = (const float*)d_in[4];
    const float* labels = (const float*)d_in[5];
    const float* W      = (const float*)d_in[6];
    const float* bb     = (const float*)d_in[7];
    const int*   nbest  = (const int*)d_in[8];

    const int N = in_sizes[5];            // labels: (N,)
    const int B = in_sizes[8];            // nBestIndex: (B,)
    const int H = in_sizes[0] / N;        // pooler: (N, H)
    const int S = in_sizes[2] / N;        // attention_mask: (N, S)

    float* out  = (float*)d_out;
    float* loss = out + N;
    float* pooled = (float*)d_ws;

    if (H == 768) {
        hipLaunchKernelGGL(pool_kernel_h768, dim3((N + 3) / 4), dim3(256), 0,
                           stream, lhs, mask, pooled, loss, N, S);
        hipLaunchKernelGGL(group_kernel, dim3(B), dim3(256), 0, stream,
                           pooler, pooled, am, ctc, W, bb, labels, nbest,
                           out, loss, N, B);
    } else {
        int* starts = (int*)((char*)d_ws + (size_t)N * H * sizeof(float));
        int* seg    = starts + (B + 1);
        hipLaunchKernelGGL(seg_kernel, dim3(1), dim3(256), 0, stream,
                           nbest, starts, seg, loss, B);
        hipLaunchKernelGGL(pool_kernel_generic, dim3(N), dim3(H / 4), 0,
                           stream, lhs, mask, pooler, am, ctc, W, bb,
                           pooled, out, S, H);
        hipLaunchKernelGGL(finale_kernel, dim3(N + B), dim3(256), 0, stream,
                           pooler, pooled, out, labels, starts, seg, loss,
                           H, N, B);
    }
}

// Round 9
// 290.938 us; speedup vs baseline: 1.1106x; 1.1106x over previous
//
#include <hip/hip_runtime.h>
#include <math.h>

typedef float f32x4 __attribute__((ext_vector_type(4)));

// out layout: d_out[0..N) = final_score (f32), d_out[N] = loss (f32)
// ws layout (H==768 fast path): pooled f32[N*H]
// ws layout (generic path):     pooled f32[N*H] | starts i32[B+1] | seg i32[N]

// ---------------- Kernel B: wave-per-row masked avg-pool -----------------
// unroll 8 => 24 dwordx4 in flight per wave (round-4 proven config; round-5
// showed fewer in-flight loads regresses even with higher occupancy).
// NONTEMPORAL LOADS ARE LOAD-BEARING: round-8 A/B removing them cost +32us
// (291->323). Read-once 1.6GB stream must bypass L2/L3 allocation.
__global__ __launch_bounds__(256, 4)
void pool_kernel_h768(const float* __restrict__ lhs,
                      const float* __restrict__ mask,
                      float* __restrict__ pooled,
                      float* __restrict__ loss,
                      int N, int S) {
    const int Hv = 192;
    if (blockIdx.x == 0 && threadIdx.x == 0) *loss = 0.f;

    const int wid  = threadIdx.x >> 6;
    const int lane = threadIdx.x & 63;
    const int j = blockIdx.x * 4 + wid;
    if (j >= N) return;

    const f32x4* row  = (const f32x4*)(lhs + (size_t)j * S * 768) + lane;
    const float* mrow = mask + (size_t)j * S;

    f32x4 a0 = {0.f,0.f,0.f,0.f}, a1 = a0, a2 = a0;
    float msum = 0.f;
#pragma unroll 8
    for (int s = 0; s < S; ++s) {
        float m = mrow[s];                  // wave-uniform addr -> 1 req/wave
        const f32x4* p = row + (size_t)s * Hv;
        f32x4 v0 = __builtin_nontemporal_load(p);
        f32x4 v1 = __builtin_nontemporal_load(p + 64);
        f32x4 v2 = __builtin_nontemporal_load(p + 128);
        a0 += v0 * m; a1 += v1 * m; a2 += v2 * m;
        msum += m;
    }
    const float inv = 1.0f / msum;
    f32x4* prow = (f32x4*)(pooled + (size_t)j * 768);
    prow[lane]       = a0 * inv;
    prow[lane + 64]  = a1 * inv;
    prow[lane + 128] = a2 * inv;
}

// ---------------- Kernel C (H==768): one block per n-best group ----------
// sz<=32 hot path: register-blocked sim GEMM. Thread owns (j, 4 r-rows):
// pj[k] read once from LDS, reused 4x; pi[r][k] are half-wave-uniform
// global loads (L1/L2-served). (Round-7 win: -17us.)
#define MAX_ROWS 40
#define PADV 193          // f32x4 units per LDS row; PADV%8==1 avoids full-bank overlap
#define MAX_SC 256

__global__ __launch_bounds__(256)
void group_kernel(const float* __restrict__ pooler,
                  const float* __restrict__ pooled,
                  const float* __restrict__ am,
                  const float* __restrict__ ctc,
                  const float* __restrict__ W,
                  const float* __restrict__ bb,
                  const float* __restrict__ labels,
                  const int* __restrict__ nbest,
                  float* __restrict__ score,
                  float* __restrict__ loss,
                  int N, int B) {
    __shared__ f32x4 s_pool[MAX_ROWS * PADV];   // ~123.5 KB
    __shared__ int   s_nb[1024];
    __shared__ float s_score[MAX_SC];
    __shared__ int   sh_s0, sh_sz;
    __shared__ float blk_loss;

    const int g = blockIdx.x;
    const int t = threadIdx.x;

    for (int i = t; i < B; i += 256) s_nb[i] = nbest[i];
    __syncthreads();
    if (t == 0) {
        int off = 0;
        for (int i = 0; i < g; ++i) off += s_nb[i];
        sh_s0 = off; sh_sz = s_nb[g];
        blk_loss = 0.f;
    }
    __syncthreads();
    const int s0 = sh_s0, sz = sh_sz;

    const int wid  = t >> 6;
    const int lane = t & 63;

    // ---- per-row linear score: [pooler_r, am_r, ctc_r] @ W + b ----------
    const f32x4* Wv = (const f32x4*)W;
    for (int r = wid; r < sz; r += 4) {
        const f32x4* pr = (const f32x4*)(pooler + (size_t)(s0 + r) * 768);
        f32x4 ps = pr[lane]       * Wv[lane]
                 + pr[lane + 64]  * Wv[lane + 64]
                 + pr[lane + 128] * Wv[lane + 128];
        float a = ps.x + ps.y + ps.z + ps.w;
        for (int d = 32; d > 0; d >>= 1) a += __shfl_xor(a, d, 64);
        if (lane == 0) {
            float sc = a + am[s0 + r] * W[768] + ctc[s0 + r] * W[769] + bb[0];
            if (sz <= MAX_SC) s_score[r] = sc;
            score[s0 + r] = sc;
        }
    }

    // ---- stage pooled group rows in LDS ---------------------------------
    const f32x4* pooled4 = (const f32x4*)pooled;
    const bool staged = (sz <= MAX_ROWS);
    if (staged) {
        for (int idx = t; idx < sz * 192; idx += 256) {
            int r = idx / 192, c = idx - r * 192;
            s_pool[r * PADV + c] = pooled4[(size_t)(s0 + r) * 192 + c];
        }
    }
    __syncthreads();

    if (sz <= 32) {
        // register-blocked: thread -> (j = lane&31, r in {r0..r0+3})
        const int j    = lane & 31;
        const int half = lane >> 5;
        const int r0   = (wid * 2 + half) * 4;
        const bool jok = (j < sz);
        const f32x4* pj = s_pool + (size_t)(jok ? j : 0) * PADV;
        const int rc0 = (r0 + 0 < sz) ? r0 + 0 : 0;
        const int rc1 = (r0 + 1 < sz) ? r0 + 1 : 0;
        const int rc2 = (r0 + 2 < sz) ? r0 + 2 : 0;
        const int rc3 = (r0 + 3 < sz) ? r0 + 3 : 0;
        const f32x4* pi0 = (const f32x4*)(pooler + (size_t)(s0 + rc0) * 768);
        const f32x4* pi1 = (const f32x4*)(pooler + (size_t)(s0 + rc1) * 768);
        const f32x4* pi2 = (const f32x4*)(pooler + (size_t)(s0 + rc2) * 768);
        const f32x4* pi3 = (const f32x4*)(pooler + (size_t)(s0 + rc3) * 768);
        f32x4 acc0 = {0.f,0.f,0.f,0.f}, acc1 = acc0, acc2 = acc0, acc3 = acc0;
#pragma unroll 4
        for (int k = 0; k < 192; ++k) {
            f32x4 pjv = pj[k];              // 1 LDS read, reused 4x
            acc0 += pi0[k] * pjv;           // half-wave-uniform global loads
            acc1 += pi1[k] * pjv;
            acc2 += pi2[k] * pjv;
            acc3 += pi3[k] * pjv;
        }
        float v0 = acc0.x + acc0.y + acc0.z + acc0.w;
        float v1 = acc1.x + acc1.y + acc1.z + acc1.w;
        float v2 = acc2.x + acc2.y + acc2.z + acc2.w;
        float v3 = acc3.x + acc3.y + acc3.z + acc3.w;
        float vv[4] = {v0, v1, v2, v3};
#pragma unroll
        for (int u = 0; u < 4; ++u) {
            const int  r   = r0 + u;
            const bool rok = (r < sz) && jok;
            float val = rok ? vv[u] : -INFINITY;
            float m = val;                  // 32-lane (half-wave) reduce
            for (int d = 1; d < 32; d <<= 1) m = fmaxf(m, __shfl_xor(m, d, 64));
            float e = rok ? expf(val - m) : 0.f;
            float ss = e;
            for (int d = 1; d < 32; d <<= 1) ss += __shfl_xor(ss, d, 64);
            if (rok && j == r)
                atomicAdd(&blk_loss, -(e / ss) / (float)B);
        }
    } else if (sz <= 64) {
        const f32x4* jbase  = staged ? s_pool : (pooled4 + (size_t)s0 * 192);
        const int    jstride = staged ? PADV : 192;
        for (int r = wid; r < sz; r += 4) {
            const bool jok = (lane < sz);
            const f32x4* pi = (const f32x4*)(pooler + (size_t)(s0 + r) * 768);
            const f32x4* pj = jbase + (size_t)(jok ? lane : 0) * jstride;
            f32x4 accA = {0.f,0.f,0.f,0.f}, accB = accA;
#pragma unroll 4
            for (int k = 0; k < 192; k += 2) {
                accA += pi[k]     * pj[k];
                accB += pi[k + 1] * pj[k + 1];
            }
            f32x4 acc4 = accA + accB;
            float val = jok ? (acc4.x + acc4.y + acc4.z + acc4.w) : -INFINITY;
            float m = val;
            for (int d = 1; d < 64; d <<= 1) m = fmaxf(m, __shfl_xor(m, d, 64));
            float e = jok ? expf(val - m) : 0.f;
            float ssum = e;
            for (int d = 1; d < 64; d <<= 1) ssum += __shfl_xor(ssum, d, 64);
            if (jok && lane == r)
                atomicAdd(&blk_loss, -(e / ssum) / (float)B);
        }
    } else {
        // generic chunked online-softmax fallback (slow path, unstaged)
        for (int r = wid; r < sz; r += 4) {
            const f32x4* pi = (const f32x4*)(pooler + (size_t)(s0 + r) * 768);
            float mrun = -INFINITY, srun = 0.f, dval = 0.f;
            for (int jc = 0; jc < sz; jc += 64) {
                const int  jx  = jc + lane;
                const bool jok = (jx < sz);
                const f32x4* pj = pooled4 + (size_t)(s0 + (jok ? jx : 0)) * 192;
                f32x4 accA = {0.f,0.f,0.f,0.f}, accB = accA;
                for (int k = 0; k < 192; k += 2) {
                    accA += pi[k]     * pj[k];
                    accB += pi[k + 1] * pj[k + 1];
                }
                f32x4 acc4 = accA + accB;
                float val = jok ? (acc4.x + acc4.y + acc4.z + acc4.w) : -INFINITY;
                float cm = val;
                for (int d = 1; d < 64; d <<= 1) cm = fmaxf(cm, __shfl_xor(cm, d, 64));
                float e = jok ? expf(val - cm) : 0.f;
                float cs = e;
                for (int d = 1; d < 64; d <<= 1) cs += __shfl_xor(cs, d, 64);
                float nm = fmaxf(mrun, cm);
                srun = srun * expf(mrun - nm) + cs * expf(cm - nm);
                float dv = __shfl(val, r - jc, 64);
                if (r >= jc && r < jc + 64) dval = dv;
                mrun = nm;
            }
            if (lane == 0)
                atomicAdd(&blk_loss, -(expf(dval - mrun) / srun) / (float)B);
        }
    }

    __syncthreads();
    // fused CE for this group (wave 0), scores from LDS
    if (wid == 0) {
        float m = -INFINITY;
        for (int idx = lane; idx < sz; idx += 64) {
            float sv = (sz <= MAX_SC) ? s_score[idx] : score[s0 + idx];
            m = fmaxf(m, sv);
        }
        for (int d = 1; d < 64; d <<= 1) m = fmaxf(m, __shfl_xor(m, d, 64));
        float s = 0.f;
        for (int idx = lane; idx < sz; idx += 64) {
            float sv = (sz <= MAX_SC) ? s_score[idx] : score[s0 + idx];
            s += expf(sv - m);
        }
        for (int d = 1; d < 64; d <<= 1) s += __shfl_xor(s, d, 64);
        const float ls = logf(s);
        float c = 0.f;
        for (int idx = lane; idx < sz; idx += 64) {
            float lb = labels[s0 + idx];
            if (lb != 0.f) {
                float sv = (sz <= MAX_SC) ? s_score[idx] : score[s0 + idx];
                c += lb * (sv - m - ls);
            }
        }
        for (int d = 1; d < 64; d <<= 1) c += __shfl_xor(c, d, 64);
        if (lane == 0) atomicAdd(&blk_loss, -c / (float)N);
    }
    __syncthreads();
    if (t == 0) atomicAdd(loss, blk_loss);
}

// =================== generic fallback path (H != 768) ====================
__global__ void seg_kernel(const int* __restrict__ nbest,
                           int* __restrict__ starts, int* __restrict__ seg,
                           float* __restrict__ loss, int B) {
    __shared__ int sh[1025];
    const int t = threadIdx.x;
    for (int g = t; g < B; g += blockDim.x) sh[g] = nbest[g];
    __syncthreads();
    if (t == 0) {
        int off = 0;
        for (int g = 0; g < B; ++g) { int v = sh[g]; sh[g] = off; off += v; }
        sh[B] = off;
        *loss = 0.f;
    }
    __syncthreads();
    for (int g = t; g <= B; g += blockDim.x) starts[g] = sh[g];
    for (int g = t; g < B; g += blockDim.x) {
        const int s0 = sh[g], s1 = sh[g + 1];
        for (int i = s0; i < s1; ++i) seg[i] = g;
    }
}

__global__ void pool_kernel_generic(const float* __restrict__ lhs,
                                    const float* __restrict__ mask,
                                    const float* __restrict__ pooler,
                                    const float* __restrict__ am,
                                    const float* __restrict__ ctc,
                                    const float* __restrict__ W,
                                    const float* __restrict__ bb,
                                    float* __restrict__ pooled,
                                    float* __restrict__ score,
                                    int S, int H) {
    const int j  = blockIdx.x;
    const int t  = threadIdx.x;
    const int Hv = H >> 2;
    const f32x4* row  = (const f32x4*)(lhs + (size_t)j * S * H);
    const float* mrow = mask + (size_t)j * S;
    f32x4 acc = {0.f,0.f,0.f,0.f};
    float msum = 0.f;
#pragma unroll 4
    for (int s = 0; s < S; ++s) {
        float m = mrow[s];
        acc += __builtin_nontemporal_load(&row[(size_t)s * Hv + t]) * m;
        msum += m;
    }
    ((f32x4*)(pooled + (size_t)j * H))[t] = acc * (1.0f / msum);
    if (t < 64) {
        const f32x4* pr = (const f32x4*)(pooler + (size_t)j * H);
        const f32x4* Wv = (const f32x4*)W;
        float a = 0.f;
        for (int k = t; k < Hv; k += 64) {
            f32x4 p = pr[k] * Wv[k];
            a += p.x + p.y + p.z + p.w;
        }
        for (int d = 32; d > 0; d >>= 1) a += __shfl_xor(a, d, 64);
        if (t == 0)
            score[j] = a + am[j] * W[H] + ctc[j] * W[H + 1] + bb[0];
    }
}

__global__ void finale_kernel(const float* __restrict__ pooler,
                              const float* __restrict__ pooled,
                              const float* __restrict__ score,
                              const float* __restrict__ labels,
                              const int* __restrict__ starts,
                              const int* __restrict__ seg,
                              float* __restrict__ loss,
                              int H, int N, int B) {
    const int bid = blockIdx.x;
    if (bid >= N) {
        const int g = bid - N;
        const int lane = threadIdx.x;
        if (lane >= 64) return;
        const int s0 = starts[g], sz = starts[g + 1] - s0;
        float m = -INFINITY;
        for (int idx = lane; idx < sz; idx += 64) m = fmaxf(m, score[s0 + idx]);
        for (int d = 32; d > 0; d >>= 1) m = fmaxf(m, __shfl_xor(m, d, 64));
        float s = 0.f;
        for (int idx = lane; idx < sz; idx += 64) s += expf(score[s0 + idx] - m);
        for (int d = 32; d > 0; d >>= 1) s += __shfl_xor(s, d, 64);
        const float ls = logf(s);
        float c = 0.f;
        for (int idx = lane; idx < sz; idx += 64) {
            float lb = labels[s0 + idx];
            if (lb != 0.f) c += lb * (score[s0 + idx] - m - ls);
        }
        for (int d = 32; d > 0; d >>= 1) c += __shfl_xor(c, d, 64);
        if (lane == 0) atomicAdd(loss, -c / (float)N);
        return;
    }
    __shared__ float simv[512];
    const int i  = bid;
    const int g  = seg[i];
    const int s0 = starts[g], sz = starts[g + 1] - s0;
    const int wid = threadIdx.x >> 6, lane = threadIdx.x & 63;
    const int nw  = blockDim.x >> 6;
    const int Hv  = H >> 2;
    const f32x4* pi = (const f32x4*)(pooler + (size_t)i * H);
    for (int j = wid; j < sz; j += nw) {
        const f32x4* pj = (const f32x4*)(pooled + (size_t)(s0 + j) * H);
        float acc = 0.f;
        for (int k = lane; k < Hv; k += 64) {
            f32x4 p = pi[k] * pj[k];
            acc += p.x + p.y + p.z + p.w;
        }
        for (int d = 32; d > 0; d >>= 1) acc += __shfl_xor(acc, d, 64);
        if (lane == 0) simv[j] = acc;
    }
    __syncthreads();
    if (wid == 0) {
        float m = -INFINITY;
        for (int idx = lane; idx < sz; idx += 64) m = fmaxf(m, simv[idx]);
        for (int d = 32; d > 0; d >>= 1) m = fmaxf(m, __shfl_xor(m, d, 64));
        float s = 0.f;
        for (int idx = lane; idx < sz; idx += 64) s += expf(simv[idx] - m);
        for (int d = 32; d > 0; d >>= 1) s += __shfl_xor(s, d, 64);
        if (lane == 0) {
            const int p = i - s0;
            const float prob = expf(simv[p] - m) / s;
            atomicAdd(loss, -prob / (float)B);
        }
    }
}

extern "C" void kernel_launch(void* const* d_in, const int* in_sizes, int n_in,
                              void* d_out, int out_size, void* d_ws, size_t ws_size,
                              hipStream_t stream) {
    const float* pooler = (const float*)d_in[0];
    const float* lhs    = (const float*)d_in[1];
    const float* mask   = (const float*)d_in[2];
    const float* am     = (const float*)d_in[3];
    const float* ctc    = (const float*)d_in[4];
    const float* labels = (const float*)d_in[5];
    const float* W      = (const float*)d_in[6];
    const float* bb     = (const float*)d_in[7];
    const int*   nbest  = (const int*)d_in[8];

    const int N = in_sizes[5];            // labels: (N,)
    const int B = in_sizes[8];            // nBestIndex: (B,)
    const int H = in_sizes[0] / N;        // pooler: (N, H)
    const int S = in_sizes[2] / N;        // attention_mask: (N, S)

    float* out  = (float*)d_out;
    float* loss = out + N;
    float* pooled = (float*)d_ws;

    if (H == 768) {
        hipLaunchKernelGGL(pool_kernel_h768, dim3((N + 3) / 4), dim3(256), 0,
                           stream, lhs, mask, pooled, loss, N, S);
        hipLaunchKernelGGL(group_kernel, dim3(B), dim3(256), 0, stream,
                           pooler, pooled, am, ctc, W, bb, labels, nbest,
                           out, loss, N, B);
    } else {
        int* starts = (int*)((char*)d_ws + (size_t)N * H * sizeof(float));
        int* seg    = starts + (B + 1);
        hipLaunchKernelGGL(seg_kernel, dim3(1), dim3(256), 0, stream,
                           nbest, starts, seg, loss, B);
        hipLaunchKernelGGL(pool_kernel_generic, dim3(N), dim3(H / 4), 0,
                           stream, lhs, mask, pooler, am, ctc, W, bb,
                           pooled, out, S, H);
        hipLaunchKernelGGL(finale_kernel, dim3(N + B), dim3(256), 0, stream,
                           pooler, pooled, out, labels, starts, seg, loss,
                           H, N, B);
    }
}